// Round 2
// baseline (578.863 us; speedup 1.0000x reference)
//
#include <hip/hip_runtime.h>
#include <hip/hip_bf16.h>

#define N_NODES 50000
#define N_EDGES 800000
#define NODE_F  128
#define EDGE_F  64
#define OUT_F   128

typedef __attribute__((ext_vector_type(8))) short short8;
typedef __attribute__((ext_vector_type(4))) short short4v;
typedef __attribute__((ext_vector_type(4))) float floatx4;

// round-to-nearest-even fp32 -> bf16
__device__ __forceinline__ unsigned short f2bf(float f) {
    unsigned int u = __float_as_uint(f);
    u += 0x7fffu + ((u >> 16) & 1u);
    return (unsigned short)(u >> 16);
}

// ---------------------------------------------------------------------------
// Kernel 1: Y[n][128] = x[n][0:128] @ W[64:192][:] + b     (no atomics)
// Block = 256 thr (4 waves), tile = 32 nodes, wave w owns N-cols [32w, 32w+32).
// ---------------------------------------------------------------------------
#define TILE_N1 32
#define N_NTILES ((N_NODES + TILE_N1 - 1) / TILE_N1)   // 1563
#define LDS_STRIDE1 136    // bf16 elems; 68 dwords ≡ 4 (mod 32) → 2-way (free)

__global__ __launch_bounds__(256, 4) void node_kernel(
    const float* __restrict__ x,
    const float* __restrict__ W,
    const float* __restrict__ bias,
    float*       __restrict__ Y)
{
    __shared__ __align__(16) unsigned short xs[TILE_N1][LDS_STRIDE1];

    const int tid  = threadIdx.x;
    const int wave = tid >> 6;
    const int lane = tid & 63;
    const int col  = lane & 15;
    const int quad = lane >> 4;
    const int wbase = wave * 32;

    const float* __restrict__ Wx = W + EDGE_F * OUT_F;   // rows 64..191

    // B-frags [4 kc][2 ns]: lane holds B[kc*32+quad*8+j][wbase+ns*16+col]
    short8 bfr[4][2];
    #pragma unroll
    for (int kc = 0; kc < 4; ++kc) {
        #pragma unroll
        for (int ns = 0; ns < 2; ++ns) {
            const int n = wbase + ns * 16 + col;
            const int krow = kc * 32 + quad * 8;
            short8 v;
            #pragma unroll
            for (int j = 0; j < 8; ++j)
                v[j] = (short)f2bf(Wx[(krow + j) * OUT_F + n]);
            bfr[kc][ns] = v;
        }
    }
    const float b0 = bias[wbase + col];
    const float b1 = bias[wbase + 16 + col];

    for (int tile = blockIdx.x; tile < N_NTILES; tile += gridDim.x) {
        const int n0 = tile * TILE_N1;

        // stage x[32][128] as bf16
        {
            const int e   = tid >> 3;      // 0..31
            const int sub = tid & 7;       // 0..7
            const int node = n0 + e;
            const float* __restrict__ xr = x + (size_t)node * NODE_F;
            #pragma unroll
            for (int i = 0; i < 4; ++i) {
                const int fi = sub + 8 * i;        // float4 index 0..31
                floatx4 v = {0.f, 0.f, 0.f, 0.f};
                if (node < N_NODES) v = *(const floatx4*)(xr + fi * 4);
                short4v sv;
                sv[0] = (short)f2bf(v[0]);
                sv[1] = (short)f2bf(v[1]);
                sv[2] = (short)f2bf(v[2]);
                sv[3] = (short)f2bf(v[3]);
                *(short4v*)&xs[e][fi * 4] = sv;
            }
        }
        __syncthreads();

        floatx4 acc[2][2] = {};
        #pragma unroll
        for (int kc = 0; kc < 4; ++kc) {
            short8 a0 = *(const short8*)&xs[col     ][kc * 32 + quad * 8];
            short8 a1 = *(const short8*)&xs[16 + col][kc * 32 + quad * 8];
            acc[0][0] = __builtin_amdgcn_mfma_f32_16x16x32_bf16(a0, bfr[kc][0], acc[0][0], 0, 0, 0);
            acc[0][1] = __builtin_amdgcn_mfma_f32_16x16x32_bf16(a0, bfr[kc][1], acc[0][1], 0, 0, 0);
            acc[1][0] = __builtin_amdgcn_mfma_f32_16x16x32_bf16(a1, bfr[kc][0], acc[1][0], 0, 0, 0);
            acc[1][1] = __builtin_amdgcn_mfma_f32_16x16x32_bf16(a1, bfr[kc][1], acc[1][1], 0, 0, 0);
        }

        #pragma unroll
        for (int ms = 0; ms < 2; ++ms) {
            #pragma unroll
            for (int r = 0; r < 4; ++r) {
                const int m = ms * 16 + quad * 4 + r;
                const int node = n0 + m;
                if (node < N_NODES) {
                    float* yrow = Y + (size_t)node * OUT_F + wbase;
                    yrow[col]      = acc[ms][0][r] + b0;
                    yrow[16 + col] = acc[ms][1][r] + b1;
                }
            }
        }
        __syncthreads();
    }
}

// ---------------------------------------------------------------------------
// Kernel 2: per-WAVE-independent edge tiles, no __syncthreads, no LDS.
// Each wave: 16 edges × (edge_attr @ W[0:64] + Y[src]) → ReLU → atomic scatter.
// B (64×128 bf16) register-resident: 16 × short8 = 64 VGPRs/lane.
// ---------------------------------------------------------------------------
#define TILE_E   16
#define N_ETILES (N_EDGES / TILE_E)   // 50000 exact
#define NBLOCKS2 1024

__global__ __launch_bounds__(256, 3) void edge_kernel(
    const float* __restrict__ edge_attr,
    const int*   __restrict__ edge_index,
    const float* __restrict__ W,        // rows 0..63 used
    const float* __restrict__ Y,
    float*       __restrict__ out)
{
    const int lane = threadIdx.x & 63;
    const int col  = lane & 15;
    const int quad = lane >> 4;

    // B-frags [2 kc][8 ns]: lane holds B[kc*32+quad*8+j][ns*16+col]
    short8 bfr[2][8];
    #pragma unroll
    for (int kc = 0; kc < 2; ++kc) {
        #pragma unroll
        for (int ns = 0; ns < 8; ++ns) {
            const int n = ns * 16 + col;
            const int krow = kc * 32 + quad * 8;
            short8 v;
            #pragma unroll
            for (int j = 0; j < 8; ++j)
                v[j] = (short)f2bf(W[(krow + j) * OUT_F + n]);
            bfr[kc][ns] = v;
        }
    }

    const int* __restrict__ srcp = edge_index;
    const int* __restrict__ dstp = edge_index + N_EDGES;

    const int gwave  = blockIdx.x * 4 + (threadIdx.x >> 6);
    const int nwaves = gridDim.x * 4;

    for (int t = gwave; t < N_ETILES; t += nwaves) {
        const int e0 = t * TILE_E;

        // A-frags: lane holds A[m=col][kc*32 + quad*8 + j] straight from global
        const float* __restrict__ ar = edge_attr + (size_t)(e0 + col) * EDGE_F;
        short8 a[2];
        #pragma unroll
        for (int kc = 0; kc < 2; ++kc) {
            floatx4 v0 = *(const floatx4*)(ar + kc * 32 + quad * 8);
            floatx4 v1 = *(const floatx4*)(ar + kc * 32 + quad * 8 + 4);
            short8 av;
            av[0] = (short)f2bf(v0[0]); av[1] = (short)f2bf(v0[1]);
            av[2] = (short)f2bf(v0[2]); av[3] = (short)f2bf(v0[3]);
            av[4] = (short)f2bf(v1[0]); av[5] = (short)f2bf(v1[1]);
            av[6] = (short)f2bf(v1[2]); av[7] = (short)f2bf(v1[3]);
            a[kc] = av;
        }

        // indices for this lane's C-rows (m = quad*4 + r)
        int sr[4], dr[4];
        #pragma unroll
        for (int r = 0; r < 4; ++r) {
            sr[r] = srcp[e0 + quad * 4 + r];
            dr[r] = dstp[e0 + quad * 4 + r];
        }

        // acc init = Y[src] gather (bias already folded into Y)
        floatx4 acc[8];
        #pragma unroll
        for (int ns = 0; ns < 8; ++ns) {
            #pragma unroll
            for (int r = 0; r < 4; ++r)
                acc[ns][r] = Y[(size_t)sr[r] * OUT_F + ns * 16 + col];
        }

        // MFMA: 2 kc × 8 ns
        #pragma unroll
        for (int kc = 0; kc < 2; ++kc) {
            #pragma unroll
            for (int ns = 0; ns < 8; ++ns)
                acc[ns] = __builtin_amdgcn_mfma_f32_16x16x32_bf16(a[kc], bfr[kc][ns], acc[ns], 0, 0, 0);
        }

        // ReLU + scatter-add (skip zeros); fire-and-forget, no drain until wave end
        #pragma unroll
        for (int ns = 0; ns < 8; ++ns) {
            #pragma unroll
            for (int r = 0; r < 4; ++r) {
                const float v = acc[ns][r];
                if (v > 0.0f)
                    atomicAdd(out + (size_t)dr[r] * OUT_F + ns * 16 + col, v);
            }
        }
    }
}

extern "C" void kernel_launch(void* const* d_in, const int* in_sizes, int n_in,
                              void* d_out, int out_size, void* d_ws, size_t ws_size,
                              hipStream_t stream) {
    const float* x          = (const float*)d_in[0];
    const int*   edge_index = (const int*)  d_in[1];
    const float* edge_attr  = (const float*)d_in[2];
    const float* W          = (const float*)d_in[3];
    const float* bias       = (const float*)d_in[4];
    float*       out        = (float*)d_out;
    float*       Y          = (float*)d_ws;   // 50000*128*4 = 25.6 MB

    hipMemsetAsync(out, 0, (size_t)out_size * sizeof(float), stream);

    node_kernel<<<dim3(512), dim3(256), 0, stream>>>(x, W, bias, Y);
    edge_kernel<<<dim3(NBLOCKS2), dim3(256), 0, stream>>>(edge_attr, edge_index, W, Y, out);
}

// Round 3
// 516.162 us; speedup vs baseline: 1.1215x; 1.1215x over previous
//
#include <hip/hip_runtime.h>
#include <hip/hip_bf16.h>

#define N_NODES 50000
#define N_EDGES 800000
#define NODE_F  128
#define EDGE_F  64
#define OUT_F   128

#define NCH ((N_NODES + 255) / 256)      // 196 scan chunks
#define EPW 128                          // edges per wave-range (6250 ranges exactly)
#define NRANGES (N_EDGES / EPW)

typedef __attribute__((ext_vector_type(8))) short short8;
typedef __attribute__((ext_vector_type(4))) short short4v;
typedef __attribute__((ext_vector_type(4))) float floatx4;

__device__ __forceinline__ unsigned short f2bf(float f) {
    unsigned int u = __float_as_uint(f);
    u += 0x7fffu + ((u >> 16) & 1u);
    return (unsigned short)(u >> 16);
}

// Load W[0:64][:] as B-fragments [2 kc][8 ns]; lane holds B[kc*32+quad*8+j][ns*16+col]
__device__ __forceinline__ void load_bfrags(const float* __restrict__ W, int col, int quad,
                                            short8 bfr[2][8]) {
    #pragma unroll
    for (int kc = 0; kc < 2; ++kc) {
        #pragma unroll
        for (int ns = 0; ns < 8; ++ns) {
            const int n = ns * 16 + col;
            const int krow = kc * 32 + quad * 8;
            short8 v;
            #pragma unroll
            for (int j = 0; j < 8; ++j)
                v[j] = (short)f2bf(W[(krow + j) * OUT_F + n]);
            bfr[kc][ns] = v;
        }
    }
}

// ---------------------------------------------------------------------------
// Kernel 1: Y[n][128] = x[n] @ W[64:192] + b   (dense GEMM, no atomics)
// ---------------------------------------------------------------------------
#define TILE_N1 32
#define N_NTILES ((N_NODES + TILE_N1 - 1) / TILE_N1)
#define LDS_STRIDE1 136

__global__ __launch_bounds__(256, 4) void node_kernel(
    const float* __restrict__ x,
    const float* __restrict__ W,
    const float* __restrict__ bias,
    float*       __restrict__ Y)
{
    __shared__ __align__(16) unsigned short xs[TILE_N1][LDS_STRIDE1];

    const int tid  = threadIdx.x;
    const int wave = tid >> 6;
    const int lane = tid & 63;
    const int col  = lane & 15;
    const int quad = lane >> 4;
    const int wbase = wave * 32;

    const float* __restrict__ Wx = W + EDGE_F * OUT_F;

    short8 bfr[4][2];
    #pragma unroll
    for (int kc = 0; kc < 4; ++kc) {
        #pragma unroll
        for (int ns = 0; ns < 2; ++ns) {
            const int n = wbase + ns * 16 + col;
            const int krow = kc * 32 + quad * 8;
            short8 v;
            #pragma unroll
            for (int j = 0; j < 8; ++j)
                v[j] = (short)f2bf(Wx[(krow + j) * OUT_F + n]);
            bfr[kc][ns] = v;
        }
    }
    const float b0 = bias[wbase + col];
    const float b1 = bias[wbase + 16 + col];

    for (int tile = blockIdx.x; tile < N_NTILES; tile += gridDim.x) {
        const int n0 = tile * TILE_N1;
        {
            const int e   = tid >> 3;
            const int sub = tid & 7;
            const int node = n0 + e;
            const float* __restrict__ xr = x + (size_t)node * NODE_F;
            #pragma unroll
            for (int i = 0; i < 4; ++i) {
                const int fi = sub + 8 * i;
                floatx4 v = {0.f, 0.f, 0.f, 0.f};
                if (node < N_NODES) v = *(const floatx4*)(xr + fi * 4);
                short4v sv;
                sv[0] = (short)f2bf(v[0]);
                sv[1] = (short)f2bf(v[1]);
                sv[2] = (short)f2bf(v[2]);
                sv[3] = (short)f2bf(v[3]);
                *(short4v*)&xs[e][fi * 4] = sv;
            }
        }
        __syncthreads();

        floatx4 acc[2][2] = {};
        #pragma unroll
        for (int kc = 0; kc < 4; ++kc) {
            short8 a0 = *(const short8*)&xs[col     ][kc * 32 + quad * 8];
            short8 a1 = *(const short8*)&xs[16 + col][kc * 32 + quad * 8];
            acc[0][0] = __builtin_amdgcn_mfma_f32_16x16x32_bf16(a0, bfr[kc][0], acc[0][0], 0, 0, 0);
            acc[0][1] = __builtin_amdgcn_mfma_f32_16x16x32_bf16(a0, bfr[kc][1], acc[0][1], 0, 0, 0);
            acc[1][0] = __builtin_amdgcn_mfma_f32_16x16x32_bf16(a1, bfr[kc][0], acc[1][0], 0, 0, 0);
            acc[1][1] = __builtin_amdgcn_mfma_f32_16x16x32_bf16(a1, bfr[kc][1], acc[1][1], 0, 0, 0);
        }

        #pragma unroll
        for (int ms = 0; ms < 2; ++ms) {
            #pragma unroll
            for (int r = 0; r < 4; ++r) {
                const int m = ms * 16 + quad * 4 + r;
                const int node = n0 + m;
                if (node < N_NODES) {
                    float* yrow = Y + (size_t)node * OUT_F + wbase;
                    yrow[col]      = acc[ms][0][r] + b0;
                    yrow[16 + col] = acc[ms][1][r] + b1;
                }
            }
        }
        __syncthreads();
    }
}

// ---------------------------------------------------------------------------
// Counting sort by dst: hist -> 3-pass scan -> scatter {eid,src,dst} as int4
// ---------------------------------------------------------------------------
__global__ void hist_kernel(const int* __restrict__ edge_index, int* __restrict__ hist) {
    const int* dstp = edge_index + N_EDGES;
    for (int i = blockIdx.x * blockDim.x + threadIdx.x; i < N_EDGES;
         i += gridDim.x * blockDim.x)
        atomicAdd(&hist[dstp[i]], 1);
}

__global__ void scan1_kernel(const int* __restrict__ hist, int* __restrict__ chunkSum) {
    __shared__ int s[256];
    const int c = blockIdx.x, t = threadIdx.x, idx = c * 256 + t;
    s[t] = (idx < N_NODES) ? hist[idx] : 0;
    __syncthreads();
    for (int off = 128; off > 0; off >>= 1) {
        if (t < off) s[t] += s[t + off];
        __syncthreads();
    }
    if (t == 0) chunkSum[c] = s[0];
}

__global__ void scan2_kernel(const int* __restrict__ chunkSum, int* __restrict__ chunkBase) {
    __shared__ int s[256];
    const int t = threadIdx.x;
    s[t] = (t < NCH) ? chunkSum[t] : 0;
    __syncthreads();
    for (int off = 1; off < 256; off <<= 1) {
        int u = (t >= off) ? s[t - off] : 0;
        __syncthreads();
        s[t] += u;
        __syncthreads();
    }
    if (t < NCH) chunkBase[t] = (t == 0) ? 0 : s[t - 1];
}

__global__ void scan3_kernel(const int* __restrict__ hist, const int* __restrict__ chunkBase,
                             int* __restrict__ row_off, int* __restrict__ cursor) {
    __shared__ int s[256];
    const int c = blockIdx.x, t = threadIdx.x, idx = c * 256 + t;
    const int v = (idx < N_NODES) ? hist[idx] : 0;
    s[t] = v;
    __syncthreads();
    for (int off = 1; off < 256; off <<= 1) {
        int u = (t >= off) ? s[t - off] : 0;
        __syncthreads();
        s[t] += u;
        __syncthreads();
    }
    const int excl = s[t] - v + chunkBase[c];
    if (idx < N_NODES) { row_off[idx] = excl; cursor[idx] = excl; }
    if (c == 0 && t == 0) row_off[N_NODES] = N_EDGES;
}

__global__ void scatter_kernel(const int* __restrict__ edge_index,
                               int* __restrict__ cursor, int4* __restrict__ sorted) {
    const int* srcp = edge_index;
    const int* dstp = edge_index + N_EDGES;
    for (int i = blockIdx.x * blockDim.x + threadIdx.x; i < N_EDGES;
         i += gridDim.x * blockDim.x) {
        const int d = dstp[i];
        const int p = atomicAdd(&cursor[d], 1);
        sorted[p] = make_int4(i, srcp[i], d, 0);
    }
}

// ---------------------------------------------------------------------------
// Kernel 2: dst-sorted edge GEMM. Wave owns every dst-run STARTING in its
// 128-edge window -> register segmented-sum -> ONE plain store per out row.
// Zero float atomics.
// ---------------------------------------------------------------------------
__device__ __forceinline__ int lbound(const int* __restrict__ ro, int target) {
    int lo = 0, hi = N_NODES;            // ro[N_NODES] = N_EDGES >= target always
    while (lo < hi) {
        const int mid = (lo + hi) >> 1;
        if (ro[mid] < target) lo = mid + 1; else hi = mid;
    }
    return lo;                           // first idx with ro[idx] >= target
}

__global__ __launch_bounds__(256, 3) void edge_gemm(
    const float* __restrict__ edge_attr,
    const float* __restrict__ W,
    const float* __restrict__ Y,
    const int*   __restrict__ row_off,
    const int4*  __restrict__ sorted,
    float*       __restrict__ out)
{
    __shared__ float CT[4][16][132];     // per-wave transpose buffer (2-way banks: free)
    __shared__ int   drow[4][16];

    const int tid  = threadIdx.x;
    const int wave = tid >> 6;
    const int lane = tid & 63;
    const int col  = lane & 15;
    const int quad = lane >> 4;

    short8 bfr[2][8];
    load_bfrags(W, col, quad, bfr);

    const int gwave = blockIdx.x * 4 + wave;
    const int nw    = gridDim.x * 4;

    for (int rg = gwave; rg < NRANGES; rg += nw) {
        const int lo = lbound(row_off, rg * EPW);
        const int hi = lbound(row_off, (rg + 1) * EPW);
        const int eb = row_off[lo];
        const int ee = row_off[hi];
        if (eb >= ee) continue;

        int   cur = -1;
        float s0 = 0.f, s1 = 0.f;

        for (int t0 = eb; t0 < ee; t0 += 16) {
            const int cnt = min(16, ee - t0);

            // A-frag: lane's edge row is sorted position t0+col (clamped pad)
            int pa = t0 + col;
            if (pa >= ee) pa = ee - 1;
            const int4 me = sorted[pa];
            const float* __restrict__ ar = edge_attr + (size_t)me.x * EDGE_F;
            short8 a[2];
            #pragma unroll
            for (int kc = 0; kc < 2; ++kc) {
                floatx4 v0 = *(const floatx4*)(ar + kc * 32 + quad * 8);
                floatx4 v1 = *(const floatx4*)(ar + kc * 32 + quad * 8 + 4);
                short8 av;
                av[0] = (short)f2bf(v0[0]); av[1] = (short)f2bf(v0[1]);
                av[2] = (short)f2bf(v0[2]); av[3] = (short)f2bf(v0[3]);
                av[4] = (short)f2bf(v1[0]); av[5] = (short)f2bf(v1[1]);
                av[6] = (short)f2bf(v1[2]); av[7] = (short)f2bf(v1[3]);
                a[kc] = av;
            }

            // segment ids for this tile (lanes 0..15 reuse their `me` load)
            if (lane < 16) drow[wave][lane] = (t0 + lane < ee) ? me.z : -1;

            // Y[src] gather rows for this lane's C rows (m = quad*4+r)
            const float* yrow[4];
            #pragma unroll
            for (int r = 0; r < 4; ++r) {
                int p = t0 + quad * 4 + r;
                if (p >= ee) p = ee - 1;
                yrow[r] = Y + (size_t)sorted[p].y * OUT_F;
            }

            floatx4 acc[8];
            #pragma unroll
            for (int ns = 0; ns < 8; ++ns) {
                #pragma unroll
                for (int r = 0; r < 4; ++r)
                    acc[ns][r] = yrow[r][ns * 16 + col];
            }

            #pragma unroll
            for (int kc = 0; kc < 2; ++kc) {
                #pragma unroll
                for (int ns = 0; ns < 8; ++ns)
                    acc[ns] = __builtin_amdgcn_mfma_f32_16x16x32_bf16(a[kc], bfr[kc][ns], acc[ns], 0, 0, 0);
            }

            // ReLU + transpose via wave-private LDS (C layout: row=quad*4+r, col n)
            #pragma unroll
            for (int ns = 0; ns < 8; ++ns) {
                #pragma unroll
                for (int r = 0; r < 4; ++r)
                    CT[wave][quad * 4 + r][ns * 16 + col] = fmaxf(acc[ns][r], 0.f);
            }
            __builtin_amdgcn_wave_barrier();   // wave-local LDS: order only, no s_barrier

            // segmented accumulate: lane owns cols {lane, lane+64}
            for (int m = 0; m < cnt; ++m) {
                const int d = drow[wave][m];
                if (d != cur) {
                    if (cur >= 0) {
                        out[(size_t)cur * OUT_F + lane]      = s0;
                        out[(size_t)cur * OUT_F + 64 + lane] = s1;
                    }
                    cur = d; s0 = 0.f; s1 = 0.f;
                }
                s0 += CT[wave][m][lane];
                s1 += CT[wave][m][64 + lane];
            }
            __builtin_amdgcn_wave_barrier();   // reads done before next tile overwrites
        }
        if (cur >= 0) {
            out[(size_t)cur * OUT_F + lane]      = s0;
            out[(size_t)cur * OUT_F + 64 + lane] = s1;
        }
    }
}

// ---------------------------------------------------------------------------
// Fallback (ws too small): R2 atomic edge kernel
// ---------------------------------------------------------------------------
__global__ __launch_bounds__(256, 3) void edge_kernel_atomic(
    const float* __restrict__ edge_attr,
    const int*   __restrict__ edge_index,
    const float* __restrict__ W,
    const float* __restrict__ Y,
    float*       __restrict__ out)
{
    const int lane = threadIdx.x & 63;
    const int col  = lane & 15;
    const int quad = lane >> 4;

    short8 bfr[2][8];
    load_bfrags(W, col, quad, bfr);

    const int* __restrict__ srcp = edge_index;
    const int* __restrict__ dstp = edge_index + N_EDGES;

    const int gwave  = blockIdx.x * 4 + (threadIdx.x >> 6);
    const int nwaves = gridDim.x * 4;

    for (int t = gwave; t < N_EDGES / 16; t += nwaves) {
        const int e0 = t * 16;
        const float* __restrict__ ar = edge_attr + (size_t)(e0 + col) * EDGE_F;
        short8 a[2];
        #pragma unroll
        for (int kc = 0; kc < 2; ++kc) {
            floatx4 v0 = *(const floatx4*)(ar + kc * 32 + quad * 8);
            floatx4 v1 = *(const floatx4*)(ar + kc * 32 + quad * 8 + 4);
            short8 av;
            av[0] = (short)f2bf(v0[0]); av[1] = (short)f2bf(v0[1]);
            av[2] = (short)f2bf(v0[2]); av[3] = (short)f2bf(v0[3]);
            av[4] = (short)f2bf(v1[0]); av[5] = (short)f2bf(v1[1]);
            av[6] = (short)f2bf(v1[2]); av[7] = (short)f2bf(v1[3]);
            a[kc] = av;
        }
        int sr[4], dr[4];
        #pragma unroll
        for (int r = 0; r < 4; ++r) {
            sr[r] = srcp[e0 + quad * 4 + r];
            dr[r] = dstp[e0 + quad * 4 + r];
        }
        floatx4 acc[8];
        #pragma unroll
        for (int ns = 0; ns < 8; ++ns)
            #pragma unroll
            for (int r = 0; r < 4; ++r)
                acc[ns][r] = Y[(size_t)sr[r] * OUT_F + ns * 16 + col];
        #pragma unroll
        for (int kc = 0; kc < 2; ++kc)
            #pragma unroll
            for (int ns = 0; ns < 8; ++ns)
                acc[ns] = __builtin_amdgcn_mfma_f32_16x16x32_bf16(a[kc], bfr[kc][ns], acc[ns], 0, 0, 0);
        #pragma unroll
        for (int ns = 0; ns < 8; ++ns)
            #pragma unroll
            for (int r = 0; r < 4; ++r) {
                const float v = acc[ns][r];
                if (v > 0.0f)
                    atomicAdd(out + (size_t)dr[r] * OUT_F + ns * 16 + col, v);
            }
    }
}

extern "C" void kernel_launch(void* const* d_in, const int* in_sizes, int n_in,
                              void* d_out, int out_size, void* d_ws, size_t ws_size,
                              hipStream_t stream) {
    const float* x          = (const float*)d_in[0];
    const int*   edge_index = (const int*)  d_in[1];
    const float* edge_attr  = (const float*)d_in[2];
    const float* W          = (const float*)d_in[3];
    const float* bias       = (const float*)d_in[4];
    float*       out        = (float*)d_out;

    // workspace layout
    float* Y        = (float*)d_ws;                          // 25.6 MB
    int4*  sorted   = (int4*)(Y + (size_t)N_NODES * OUT_F);  // 12.8 MB (16B-aligned)
    int*   hist     = (int*)(sorted + N_EDGES);
    int*   chunkSum = hist + N_NODES;
    int*   chunkBase= chunkSum + 256;
    int*   row_off  = chunkBase + 256;                       // N_NODES+1
    int*   cursor   = row_off + N_NODES + 1;                 // N_NODES
    const size_t needed = (size_t)((char*)(cursor + N_NODES) - (char*)d_ws);

    hipMemsetAsync(out, 0, (size_t)out_size * sizeof(float), stream);
    node_kernel<<<dim3(512), dim3(256), 0, stream>>>(x, W, bias, Y);

    if (ws_size < needed) {   // fallback: atomic scatter path
        edge_kernel_atomic<<<dim3(1024), dim3(256), 0, stream>>>(edge_attr, edge_index, W, Y, out);
        return;
    }

    hipMemsetAsync(hist, 0, (size_t)N_NODES * sizeof(int), stream);
    hist_kernel   <<<dim3(2048), dim3(256), 0, stream>>>(edge_index, hist);
    scan1_kernel  <<<dim3(NCH),  dim3(256), 0, stream>>>(hist, chunkSum);
    scan2_kernel  <<<dim3(1),    dim3(256), 0, stream>>>(chunkSum, chunkBase);
    scan3_kernel  <<<dim3(NCH),  dim3(256), 0, stream>>>(hist, chunkBase, row_off, cursor);
    scatter_kernel<<<dim3(2048), dim3(256), 0, stream>>>(edge_index, cursor, sorted);
    edge_gemm     <<<dim3(1563), dim3(256), 0, stream>>>(edge_attr, W, Y, row_off, sorted, out);
}

// Round 4
// 488.037 us; speedup vs baseline: 1.1861x; 1.0576x over previous
//
#include <hip/hip_runtime.h>
#include <hip/hip_bf16.h>

#define N_NODES 50000
#define N_EDGES 800000
#define NODE_F  128
#define EDGE_F  64
#define OUT_F   128

#define NCH ((N_NODES + 255) / 256)      // 196 scan chunks
#define EPW 128                          // edges per range (1 range : 2 waves)
#define NRANGES (N_EDGES / EPW)          // 6250

typedef __attribute__((ext_vector_type(8))) short short8;
typedef __attribute__((ext_vector_type(4))) short short4v;
typedef __attribute__((ext_vector_type(4))) float floatx4;

__device__ __forceinline__ unsigned short f2bf(float f) {
    unsigned int u = __float_as_uint(f);
    u += 0x7fffu + ((u >> 16) & 1u);
    return (unsigned short)(u >> 16);
}

// ---------------------------------------------------------------------------
// Kernel 1: Y[n][128] = x[n] @ W[64:192] + b   (dense GEMM, no atomics)
// ---------------------------------------------------------------------------
#define TILE_N1 32
#define N_NTILES ((N_NODES + TILE_N1 - 1) / TILE_N1)
#define LDS_STRIDE1 136

__global__ __launch_bounds__(256, 4) void node_kernel(
    const float* __restrict__ x,
    const float* __restrict__ W,
    const float* __restrict__ bias,
    float*       __restrict__ Y)
{
    __shared__ __align__(16) unsigned short xs[TILE_N1][LDS_STRIDE1];

    const int tid  = threadIdx.x;
    const int wave = tid >> 6;
    const int lane = tid & 63;
    const int col  = lane & 15;
    const int quad = lane >> 4;
    const int wbase = wave * 32;

    const float* __restrict__ Wx = W + EDGE_F * OUT_F;

    short8 bfr[4][2];
    #pragma unroll
    for (int kc = 0; kc < 4; ++kc) {
        #pragma unroll
        for (int ns = 0; ns < 2; ++ns) {
            const int n = wbase + ns * 16 + col;
            const int krow = kc * 32 + quad * 8;
            short8 v;
            #pragma unroll
            for (int j = 0; j < 8; ++j)
                v[j] = (short)f2bf(Wx[(krow + j) * OUT_F + n]);
            bfr[kc][ns] = v;
        }
    }
    const float b0 = bias[wbase + col];
    const float b1 = bias[wbase + 16 + col];

    for (int tile = blockIdx.x; tile < N_NTILES; tile += gridDim.x) {
        const int n0 = tile * TILE_N1;
        {
            const int e   = tid >> 3;
            const int sub = tid & 7;
            const int node = n0 + e;
            const float* __restrict__ xr = x + (size_t)node * NODE_F;
            #pragma unroll
            for (int i = 0; i < 4; ++i) {
                const int fi = sub + 8 * i;
                floatx4 v = {0.f, 0.f, 0.f, 0.f};
                if (node < N_NODES) v = *(const floatx4*)(xr + fi * 4);
                short4v sv;
                sv[0] = (short)f2bf(v[0]);
                sv[1] = (short)f2bf(v[1]);
                sv[2] = (short)f2bf(v[2]);
                sv[3] = (short)f2bf(v[3]);
                *(short4v*)&xs[e][fi * 4] = sv;
            }
        }
        __syncthreads();

        floatx4 acc[2][2] = {};
        #pragma unroll
        for (int kc = 0; kc < 4; ++kc) {
            short8 a0 = *(const short8*)&xs[col     ][kc * 32 + quad * 8];
            short8 a1 = *(const short8*)&xs[16 + col][kc * 32 + quad * 8];
            acc[0][0] = __builtin_amdgcn_mfma_f32_16x16x32_bf16(a0, bfr[kc][0], acc[0][0], 0, 0, 0);
            acc[0][1] = __builtin_amdgcn_mfma_f32_16x16x32_bf16(a0, bfr[kc][1], acc[0][1], 0, 0, 0);
            acc[1][0] = __builtin_amdgcn_mfma_f32_16x16x32_bf16(a1, bfr[kc][0], acc[1][0], 0, 0, 0);
            acc[1][1] = __builtin_amdgcn_mfma_f32_16x16x32_bf16(a1, bfr[kc][1], acc[1][1], 0, 0, 0);
        }

        #pragma unroll
        for (int ms = 0; ms < 2; ++ms) {
            #pragma unroll
            for (int r = 0; r < 4; ++r) {
                const int m = ms * 16 + quad * 4 + r;
                const int node = n0 + m;
                if (node < N_NODES) {
                    float* yrow = Y + (size_t)node * OUT_F + wbase;
                    yrow[col]      = acc[ms][0][r] + b0;
                    yrow[16 + col] = acc[ms][1][r] + b1;
                }
            }
        }
        __syncthreads();
    }
}

// ---------------------------------------------------------------------------
// Counting sort by dst
// ---------------------------------------------------------------------------
__global__ void hist_kernel(const int* __restrict__ edge_index, int* __restrict__ hist) {
    const int* dstp = edge_index + N_EDGES;
    for (int i = blockIdx.x * blockDim.x + threadIdx.x; i < N_EDGES;
         i += gridDim.x * blockDim.x)
        atomicAdd(&hist[dstp[i]], 1);
}

__global__ void scan1_kernel(const int* __restrict__ hist, int* __restrict__ chunkSum) {
    __shared__ int s[256];
    const int c = blockIdx.x, t = threadIdx.x, idx = c * 256 + t;
    s[t] = (idx < N_NODES) ? hist[idx] : 0;
    __syncthreads();
    for (int off = 128; off > 0; off >>= 1) {
        if (t < off) s[t] += s[t + off];
        __syncthreads();
    }
    if (t == 0) chunkSum[c] = s[0];
}

__global__ void scan2_kernel(const int* __restrict__ chunkSum, int* __restrict__ chunkBase) {
    __shared__ int s[256];
    const int t = threadIdx.x;
    s[t] = (t < NCH) ? chunkSum[t] : 0;
    __syncthreads();
    for (int off = 1; off < 256; off <<= 1) {
        int u = (t >= off) ? s[t - off] : 0;
        __syncthreads();
        s[t] += u;
        __syncthreads();
    }
    if (t < NCH) chunkBase[t] = (t == 0) ? 0 : s[t - 1];
}

__global__ void scan3_kernel(const int* __restrict__ hist, const int* __restrict__ chunkBase,
                             int* __restrict__ row_off, int* __restrict__ cursor) {
    __shared__ int s[256];
    const int c = blockIdx.x, t = threadIdx.x, idx = c * 256 + t;
    const int v = (idx < N_NODES) ? hist[idx] : 0;
    s[t] = v;
    __syncthreads();
    for (int off = 1; off < 256; off <<= 1) {
        int u = (t >= off) ? s[t - off] : 0;
        __syncthreads();
        s[t] += u;
        __syncthreads();
    }
    const int excl = s[t] - v + chunkBase[c];
    if (idx < N_NODES) { row_off[idx] = excl; cursor[idx] = excl; }
    if (c == 0 && t == 0) row_off[N_NODES] = N_EDGES;
}

__device__ __forceinline__ int lbound(const int* __restrict__ ro, int target) {
    int lo = 0, hi = N_NODES;
    while (lo < hi) {
        const int mid = (lo + hi) >> 1;
        if (ro[mid] < target) lo = mid + 1; else hi = mid;
    }
    return lo;
}

// precompute range -> first-node mapping (kills per-wave binary searches)
__global__ void range_kernel(const int* __restrict__ row_off, int* __restrict__ range_lo) {
    const int rg = blockIdx.x * blockDim.x + threadIdx.x;
    if (rg <= NRANGES) range_lo[rg] = lbound(row_off, rg * EPW);
}

__global__ void scatter_kernel(const int* __restrict__ edge_index,
                               int* __restrict__ cursor, int4* __restrict__ sorted) {
    const int* srcp = edge_index;
    const int* dstp = edge_index + N_EDGES;
    for (int i = blockIdx.x * blockDim.x + threadIdx.x; i < N_EDGES;
         i += gridDim.x * blockDim.x) {
        const int d = dstp[i];
        const int p = atomicAdd(&cursor[d], 1);
        sorted[p] = make_int4(i, srcp[i], d, 0);
    }
}

// ---------------------------------------------------------------------------
// Kernel 2 v2: dst-sorted edge GEMM.
//   - 2 waves per 128-edge range; wave parity p owns output cols [64p, 64p+64)
//   - pad-to-16 tiles, fully-unrolled reduce, dst via readlane (no drow LDS)
//   - range bounds precomputed; one plain store per (node, col-half)
// ---------------------------------------------------------------------------
__global__ __launch_bounds__(256, 4) void edge_gemm(
    const float* __restrict__ edge_attr,
    const float* __restrict__ W,
    const float* __restrict__ Y,
    const int*   __restrict__ row_off,
    const int*   __restrict__ range_lo,
    const int4*  __restrict__ sorted,
    float*       __restrict__ out)
{
    __shared__ float CT[4][16][68];   // per-wave msg^relu tile; quad bank-shift 16 -> free 2-way

    const int tid  = threadIdx.x;
    const int wave = tid >> 6;
    const int lane = tid & 63;
    const int col  = lane & 15;
    const int quad = lane >> 4;
    const int p    = wave & 1;        // col-half

    // B-frags for this wave's 64 cols: [2 kc][4 ns]
    short8 bfr[2][4];
    #pragma unroll
    for (int kc = 0; kc < 2; ++kc) {
        #pragma unroll
        for (int ns = 0; ns < 4; ++ns) {
            const int n = p * 64 + ns * 16 + col;
            const int krow = kc * 32 + quad * 8;
            short8 v;
            #pragma unroll
            for (int j = 0; j < 8; ++j)
                v[j] = (short)f2bf(W[(krow + j) * OUT_F + n]);
            bfr[kc][ns] = v;
        }
    }

    const int grange = blockIdx.x * 2 + (wave >> 1);
    const int stride = gridDim.x * 2;

    for (int rg = grange; rg < NRANGES; rg += stride) {
        const int eb = row_off[range_lo[rg]];
        const int ee = row_off[range_lo[rg + 1]];
        if (eb >= ee) continue;

        int   cur = -1;
        float s   = 0.f;

        // first tile's sorted entries + A-frags
        int4 me = sorted[min(eb + col, ee - 1)];
        short8 a[2];
        {
            const float* __restrict__ ar = edge_attr + (size_t)me.x * EDGE_F;
            #pragma unroll
            for (int kc = 0; kc < 2; ++kc) {
                floatx4 v0 = *(const floatx4*)(ar + kc * 32 + quad * 8);
                floatx4 v1 = *(const floatx4*)(ar + kc * 32 + quad * 8 + 4);
                short8 av;
                av[0] = (short)f2bf(v0[0]); av[1] = (short)f2bf(v0[1]);
                av[2] = (short)f2bf(v0[2]); av[3] = (short)f2bf(v0[3]);
                av[4] = (short)f2bf(v1[0]); av[5] = (short)f2bf(v1[1]);
                av[6] = (short)f2bf(v1[2]); av[7] = (short)f2bf(v1[3]);
                a[kc] = av;
            }
        }

        for (int t0 = eb; t0 < ee; t0 += 16) {
            // ---- acc init = Y[src] gather for this wave's col-half ----
            floatx4 acc[4];
            #pragma unroll
            for (int r = 0; r < 4; ++r) {
                const int src = __shfl(me.y, quad * 4 + r);   // lane m holds sorted[t0+m]
                const float* __restrict__ yr = Y + (size_t)src * OUT_F + p * 64;
                #pragma unroll
                for (int ns = 0; ns < 4; ++ns)
                    acc[ns][r] = yr[ns * 16 + col];
            }

            // ---- MFMA: [16 edges x 64 cols], K=64 ----
            #pragma unroll
            for (int kc = 0; kc < 2; ++kc) {
                #pragma unroll
                for (int ns = 0; ns < 4; ++ns)
                    acc[ns] = __builtin_amdgcn_mfma_f32_16x16x32_bf16(a[kc], bfr[kc][ns], acc[ns], 0, 0, 0);
            }

            // ---- ReLU -> CT (pad rows write 0 so reduce can be branch-light) ----
            #pragma unroll
            for (int r = 0; r < 4; ++r) {
                const bool rvalid = (t0 + quad * 4 + r) < ee;
                #pragma unroll
                for (int ns = 0; ns < 4; ++ns)
                    CT[wave][quad * 4 + r][ns * 16 + col] =
                        rvalid ? fmaxf(acc[ns][r], 0.f) : 0.f;
            }
            __builtin_amdgcn_wave_barrier();

            // ---- prefetch next tile's sorted entries (overlaps reduce) ----
            const int t1 = t0 + 16;
            int4 me2;
            if (t1 < ee) me2 = sorted[min(t1 + col, ee - 1)];

            // ---- reduce: batched LDS reads + uniform scalar flush ----
            float cv[16];
            #pragma unroll
            for (int m = 0; m < 16; ++m) cv[m] = CT[wave][m][lane];

            #pragma unroll
            for (int m = 0; m < 16; ++m) {
                const int d = __builtin_amdgcn_readlane(me.z, m);  // uniform dst of row m
                if (d != cur) {
                    if (cur >= 0) out[(size_t)cur * OUT_F + p * 64 + lane] = s;
                    cur = d; s = 0.f;
                }
                s += cv[m];
            }
            cur = __builtin_amdgcn_readfirstlane(cur);
            __builtin_amdgcn_wave_barrier();

            // ---- next tile's A-frags ----
            if (t1 < ee) {
                me = me2;
                const float* __restrict__ ar = edge_attr + (size_t)me.x * EDGE_F;
                #pragma unroll
                for (int kc = 0; kc < 2; ++kc) {
                    floatx4 v0 = *(const floatx4*)(ar + kc * 32 + quad * 8);
                    floatx4 v1 = *(const floatx4*)(ar + kc * 32 + quad * 8 + 4);
                    short8 av;
                    av[0] = (short)f2bf(v0[0]); av[1] = (short)f2bf(v0[1]);
                    av[2] = (short)f2bf(v0[2]); av[3] = (short)f2bf(v0[3]);
                    av[4] = (short)f2bf(v1[0]); av[5] = (short)f2bf(v1[1]);
                    av[6] = (short)f2bf(v1[2]); av[7] = (short)f2bf(v1[3]);
                    a[kc] = av;
                }
            }
        }
        if (cur >= 0) out[(size_t)cur * OUT_F + p * 64 + lane] = s;
    }
}

// ---------------------------------------------------------------------------
// Fallback (ws too small): atomic edge kernel
// ---------------------------------------------------------------------------
__global__ __launch_bounds__(256, 3) void edge_kernel_atomic(
    const float* __restrict__ edge_attr,
    const int*   __restrict__ edge_index,
    const float* __restrict__ W,
    const float* __restrict__ Y,
    float*       __restrict__ out)
{
    const int lane = threadIdx.x & 63;
    const int col  = lane & 15;
    const int quad = lane >> 4;

    short8 bfr[2][8];
    #pragma unroll
    for (int kc = 0; kc < 2; ++kc)
        #pragma unroll
        for (int ns = 0; ns < 8; ++ns) {
            const int n = ns * 16 + col;
            const int krow = kc * 32 + quad * 8;
            short8 v;
            #pragma unroll
            for (int j = 0; j < 8; ++j)
                v[j] = (short)f2bf(W[(krow + j) * OUT_F + n]);
            bfr[kc][ns] = v;
        }

    const int* __restrict__ srcp = edge_index;
    const int* __restrict__ dstp = edge_index + N_EDGES;

    const int gwave  = blockIdx.x * 4 + (threadIdx.x >> 6);
    const int nwaves = gridDim.x * 4;

    for (int t = gwave; t < N_EDGES / 16; t += nwaves) {
        const int e0 = t * 16;
        const float* __restrict__ ar = edge_attr + (size_t)(e0 + col) * EDGE_F;
        short8 a[2];
        #pragma unroll
        for (int kc = 0; kc < 2; ++kc) {
            floatx4 v0 = *(const floatx4*)(ar + kc * 32 + quad * 8);
            floatx4 v1 = *(const floatx4*)(ar + kc * 32 + quad * 8 + 4);
            short8 av;
            av[0] = (short)f2bf(v0[0]); av[1] = (short)f2bf(v0[1]);
            av[2] = (short)f2bf(v0[2]); av[3] = (short)f2bf(v0[3]);
            av[4] = (short)f2bf(v1[0]); av[5] = (short)f2bf(v1[1]);
            av[6] = (short)f2bf(v1[2]); av[7] = (short)f2bf(v1[3]);
            a[kc] = av;
        }
        int sr[4], dr[4];
        #pragma unroll
        for (int r = 0; r < 4; ++r) {
            sr[r] = srcp[e0 + quad * 4 + r];
            dr[r] = dstp[e0 + quad * 4 + r];
        }
        floatx4 acc[8];
        #pragma unroll
        for (int ns = 0; ns < 8; ++ns)
            #pragma unroll
            for (int r = 0; r < 4; ++r)
                acc[ns][r] = Y[(size_t)sr[r] * OUT_F + ns * 16 + col];
        #pragma unroll
        for (int kc = 0; kc < 2; ++kc)
            #pragma unroll
            for (int ns = 0; ns < 8; ++ns)
                acc[ns] = __builtin_amdgcn_mfma_f32_16x16x32_bf16(a[kc], bfr[kc][ns], acc[ns], 0, 0, 0);
        #pragma unroll
        for (int ns = 0; ns < 8; ++ns)
            #pragma unroll
            for (int r = 0; r < 4; ++r) {
                const float v = acc[ns][r];
                if (v > 0.0f)
                    atomicAdd(out + (size_t)dr[r] * OUT_F + ns * 16 + col, v);
            }
    }
}

extern "C" void kernel_launch(void* const* d_in, const int* in_sizes, int n_in,
                              void* d_out, int out_size, void* d_ws, size_t ws_size,
                              hipStream_t stream) {
    const float* x          = (const float*)d_in[0];
    const int*   edge_index = (const int*)  d_in[1];
    const float* edge_attr  = (const float*)d_in[2];
    const float* W          = (const float*)d_in[3];
    const float* bias       = (const float*)d_in[4];
    float*       out        = (float*)d_out;

    // workspace layout
    float* Y        = (float*)d_ws;                          // 25.6 MB
    int4*  sorted   = (int4*)(Y + (size_t)N_NODES * OUT_F);  // 12.8 MB
    int*   hist     = (int*)(sorted + N_EDGES);
    int*   chunkSum = hist + N_NODES;
    int*   chunkBase= chunkSum + 256;
    int*   row_off  = chunkBase + 256;                       // N_NODES+1
    int*   cursor   = row_off + N_NODES + 1;                 // N_NODES
    int*   range_lo = cursor + N_NODES;                      // NRANGES+1
    const size_t needed = (size_t)((char*)(range_lo + NRANGES + 1) - (char*)d_ws);

    hipMemsetAsync(out, 0, (size_t)out_size * sizeof(float), stream);
    node_kernel<<<dim3(512), dim3(256), 0, stream>>>(x, W, bias, Y);

    if (ws_size < needed) {
        edge_kernel_atomic<<<dim3(1024), dim3(256), 0, stream>>>(edge_attr, edge_index, W, Y, out);
        return;
    }

    hipMemsetAsync(hist, 0, (size_t)N_NODES * sizeof(int), stream);
    hist_kernel   <<<dim3(2048), dim3(256), 0, stream>>>(edge_index, hist);
    scan1_kernel  <<<dim3(NCH),  dim3(256), 0, stream>>>(hist, chunkSum);
    scan2_kernel  <<<dim3(1),    dim3(256), 0, stream>>>(chunkSum, chunkBase);
    scan3_kernel  <<<dim3(NCH),  dim3(256), 0, stream>>>(hist, chunkBase, row_off, cursor);
    range_kernel  <<<dim3((NRANGES + 256) / 256), dim3(256), 0, stream>>>(row_off, range_lo);
    scatter_kernel<<<dim3(2048), dim3(256), 0, stream>>>(edge_index, cursor, sorted);
    edge_gemm     <<<dim3((NRANGES + 1) / 2), dim3(256), 0, stream>>>(
        edge_attr, W, Y, row_off, range_lo, sorted, out);
}

// Round 5
// 483.766 us; speedup vs baseline: 1.1966x; 1.0088x over previous
//
#include <hip/hip_runtime.h>
#include <hip/hip_bf16.h>

#define N_NODES 50000
#define N_EDGES 800000
#define NODE_F  128
#define EDGE_F  64
#define OUT_F   128

#define NCH ((N_NODES + 255) / 256)      // 196 scan chunks
#define EPW 128                          // edges per range (1 range : 2 waves)
#define NRANGES (N_EDGES / EPW)          // 6250

typedef __attribute__((ext_vector_type(8))) short short8;
typedef __attribute__((ext_vector_type(4))) short short4v;
typedef __attribute__((ext_vector_type(4))) float floatx4;

__device__ __forceinline__ unsigned short f2bf(float f) {
    unsigned int u = __float_as_uint(f);
    u += 0x7fffu + ((u >> 16) & 1u);
    return (unsigned short)(u >> 16);
}

// packed RNE convert: 8 floats -> short8 bf16 via v_cvt_pk_bf16_f32
__device__ __forceinline__ short8 cvt8(floatx4 v0, floatx4 v1) {
    union { __hip_bfloat162 h[4]; short8 s; } u;
    u.h[0] = __float22bfloat162_rn(make_float2(v0[0], v0[1]));
    u.h[1] = __float22bfloat162_rn(make_float2(v0[2], v0[3]));
    u.h[2] = __float22bfloat162_rn(make_float2(v1[0], v1[1]));
    u.h[3] = __float22bfloat162_rn(make_float2(v1[2], v1[3]));
    return u.s;
}

// ---------------------------------------------------------------------------
// Kernel 1: Y[n][128] = x[n] @ W[64:192] + b   (dense GEMM, no atomics)
// ---------------------------------------------------------------------------
#define TILE_N1 32
#define N_NTILES ((N_NODES + TILE_N1 - 1) / TILE_N1)
#define LDS_STRIDE1 136

__global__ __launch_bounds__(256, 4) void node_kernel(
    const float* __restrict__ x,
    const float* __restrict__ W,
    const float* __restrict__ bias,
    float*       __restrict__ Y)
{
    __shared__ __align__(16) unsigned short xs[TILE_N1][LDS_STRIDE1];

    const int tid  = threadIdx.x;
    const int wave = tid >> 6;
    const int lane = tid & 63;
    const int col  = lane & 15;
    const int quad = lane >> 4;
    const int wbase = wave * 32;

    const float* __restrict__ Wx = W + EDGE_F * OUT_F;

    short8 bfr[4][2];
    #pragma unroll
    for (int kc = 0; kc < 4; ++kc) {
        #pragma unroll
        for (int ns = 0; ns < 2; ++ns) {
            const int n = wbase + ns * 16 + col;
            const int krow = kc * 32 + quad * 8;
            short8 v;
            #pragma unroll
            for (int j = 0; j < 8; ++j)
                v[j] = (short)f2bf(Wx[(krow + j) * OUT_F + n]);
            bfr[kc][ns] = v;
        }
    }
    const float b0 = bias[wbase + col];
    const float b1 = bias[wbase + 16 + col];

    for (int tile = blockIdx.x; tile < N_NTILES; tile += gridDim.x) {
        const int n0 = tile * TILE_N1;
        {
            const int e   = tid >> 3;
            const int sub = tid & 7;
            const int node = n0 + e;
            const float* __restrict__ xr = x + (size_t)node * NODE_F;
            #pragma unroll
            for (int i = 0; i < 4; ++i) {
                const int fi = sub + 8 * i;
                floatx4 v = {0.f, 0.f, 0.f, 0.f};
                if (node < N_NODES) v = *(const floatx4*)(xr + fi * 4);
                union { __hip_bfloat162 h[2]; short4v s; } u;
                u.h[0] = __float22bfloat162_rn(make_float2(v[0], v[1]));
                u.h[1] = __float22bfloat162_rn(make_float2(v[2], v[3]));
                *(short4v*)&xs[e][fi * 4] = u.s;
            }
        }
        __syncthreads();

        floatx4 acc[2][2] = {};
        #pragma unroll
        for (int kc = 0; kc < 4; ++kc) {
            short8 a0 = *(const short8*)&xs[col     ][kc * 32 + quad * 8];
            short8 a1 = *(const short8*)&xs[16 + col][kc * 32 + quad * 8];
            acc[0][0] = __builtin_amdgcn_mfma_f32_16x16x32_bf16(a0, bfr[kc][0], acc[0][0], 0, 0, 0);
            acc[0][1] = __builtin_amdgcn_mfma_f32_16x16x32_bf16(a0, bfr[kc][1], acc[0][1], 0, 0, 0);
            acc[1][0] = __builtin_amdgcn_mfma_f32_16x16x32_bf16(a1, bfr[kc][0], acc[1][0], 0, 0, 0);
            acc[1][1] = __builtin_amdgcn_mfma_f32_16x16x32_bf16(a1, bfr[kc][1], acc[1][1], 0, 0, 0);
        }

        #pragma unroll
        for (int ms = 0; ms < 2; ++ms) {
            #pragma unroll
            for (int r = 0; r < 4; ++r) {
                const int m = ms * 16 + quad * 4 + r;
                const int node = n0 + m;
                if (node < N_NODES) {
                    float* yrow = Y + (size_t)node * OUT_F + wbase;
                    yrow[col]      = acc[ms][0][r] + b0;
                    yrow[16 + col] = acc[ms][1][r] + b1;
                }
            }
        }
        __syncthreads();
    }
}

// ---------------------------------------------------------------------------
// Counting sort by dst
// ---------------------------------------------------------------------------
__global__ void hist_kernel(const int* __restrict__ edge_index, int* __restrict__ hist) {
    const int* dstp = edge_index + N_EDGES;
    for (int i = blockIdx.x * blockDim.x + threadIdx.x; i < N_EDGES;
         i += gridDim.x * blockDim.x)
        atomicAdd(&hist[dstp[i]], 1);
}

__global__ void scan1_kernel(const int* __restrict__ hist, int* __restrict__ chunkSum) {
    __shared__ int s[256];
    const int c = blockIdx.x, t = threadIdx.x, idx = c * 256 + t;
    s[t] = (idx < N_NODES) ? hist[idx] : 0;
    __syncthreads();
    for (int off = 128; off > 0; off >>= 1) {
        if (t < off) s[t] += s[t + off];
        __syncthreads();
    }
    if (t == 0) chunkSum[c] = s[0];
}

__global__ void scan2_kernel(const int* __restrict__ chunkSum, int* __restrict__ chunkBase) {
    __shared__ int s[256];
    const int t = threadIdx.x;
    s[t] = (t < NCH) ? chunkSum[t] : 0;
    __syncthreads();
    for (int off = 1; off < 256; off <<= 1) {
        int u = (t >= off) ? s[t - off] : 0;
        __syncthreads();
        s[t] += u;
        __syncthreads();
    }
    if (t < NCH) chunkBase[t] = (t == 0) ? 0 : s[t - 1];
}

__global__ void scan3_kernel(const int* __restrict__ hist, const int* __restrict__ chunkBase,
                             int* __restrict__ row_off, int* __restrict__ cursor) {
    __shared__ int s[256];
    const int c = blockIdx.x, t = threadIdx.x, idx = c * 256 + t;
    const int v = (idx < N_NODES) ? hist[idx] : 0;
    s[t] = v;
    __syncthreads();
    for (int off = 1; off < 256; off <<= 1) {
        int u = (t >= off) ? s[t - off] : 0;
        __syncthreads();
        s[t] += u;
        __syncthreads();
    }
    const int excl = s[t] - v + chunkBase[c];
    if (idx < N_NODES) { row_off[idx] = excl; cursor[idx] = excl; }
    if (c == 0 && t == 0) row_off[N_NODES] = N_EDGES;
}

__device__ __forceinline__ int lbound(const int* __restrict__ ro, int target) {
    int lo = 0, hi = N_NODES;
    while (lo < hi) {
        const int mid = (lo + hi) >> 1;
        if (ro[mid] < target) lo = mid + 1; else hi = mid;
    }
    return lo;
}

// range -> starting EDGE offset (direct, one load in edge_gemm)
__global__ void range_kernel(const int* __restrict__ row_off, int* __restrict__ range_start) {
    const int rg = blockIdx.x * blockDim.x + threadIdx.x;
    if (rg <= NRANGES) range_start[rg] = row_off[lbound(row_off, rg * EPW)];
}

__global__ void scatter_kernel(const int* __restrict__ edge_index,
                               int* __restrict__ cursor, int2* __restrict__ sorted) {
    const int* srcp = edge_index;
    const int* dstp = edge_index + N_EDGES;
    for (int i = blockIdx.x * blockDim.x + threadIdx.x; i < N_EDGES;
         i += gridDim.x * blockDim.x) {
        const int d = dstp[i];
        const int p = atomicAdd(&cursor[d], 1);
        sorted[p] = make_int2(i, (int)(((unsigned)srcp[i] << 16) | (unsigned)d));
    }
}

// ---------------------------------------------------------------------------
// Kernel 2 v3: dst-sorted edge GEMM.
//   - 2 waves per 128-edge range; wave parity p owns output cols [64p, 64p+64)
//   - grid-stride over ranges; launch_bounds(256,6) -> 24 waves/CU
//   - sorted payload int2 {eid, src<<16|dst}; range_start direct edge offsets
// ---------------------------------------------------------------------------
__global__ __launch_bounds__(256, 6) void edge_gemm(
    const float* __restrict__ edge_attr,
    const float* __restrict__ W,
    const float* __restrict__ Y,
    const int*   __restrict__ range_start,
    const int2*  __restrict__ sorted,
    float*       __restrict__ out)
{
    __shared__ float CT[4][16][68];   // per-wave tile; quad bank-shift 16 -> free 2-way

    const int tid  = threadIdx.x;
    const int wave = tid >> 6;
    const int lane = tid & 63;
    const int col  = lane & 15;
    const int quad = lane >> 4;
    const int p    = wave & 1;        // col-half

    // B-frags for this wave's 64 cols: [2 kc][4 ns]
    short8 bfr[2][4];
    #pragma unroll
    for (int kc = 0; kc < 2; ++kc) {
        #pragma unroll
        for (int ns = 0; ns < 4; ++ns) {
            const int n = p * 64 + ns * 16 + col;
            const int krow = kc * 32 + quad * 8;
            short8 v;
            #pragma unroll
            for (int j = 0; j < 8; ++j)
                v[j] = (short)f2bf(W[(krow + j) * OUT_F + n]);
            bfr[kc][ns] = v;
        }
    }

    float* __restrict__ obase = out + p * 64 + lane;

    const int grange = blockIdx.x * 2 + (wave >> 1);
    const int stride = gridDim.x * 2;

    for (int rg = grange; rg < NRANGES; rg += stride) {
        const int eb = range_start[rg];
        const int ee = range_start[rg + 1];
        if (eb >= ee) continue;

        int   cur = -1;
        float s   = 0.f;

        // first tile's sorted entries + A-frags
        int2 me = sorted[min(eb + col, ee - 1)];
        short8 a[2];
        {
            const float* __restrict__ ar = edge_attr + (size_t)me.x * EDGE_F;
            #pragma unroll
            for (int kc = 0; kc < 2; ++kc)
                a[kc] = cvt8(*(const floatx4*)(ar + kc * 32 + quad * 8),
                             *(const floatx4*)(ar + kc * 32 + quad * 8 + 4));
        }

        for (int t0 = eb; t0 < ee; t0 += 16) {
            // ---- acc init = Y[src] gather for this wave's col-half ----
            floatx4 acc[4];
            #pragma unroll
            for (int r = 0; r < 4; ++r) {
                const int src = (int)((unsigned)__shfl(me.y, quad * 4 + r) >> 16);
                const float* __restrict__ yr = Y + (size_t)src * OUT_F + p * 64;
                #pragma unroll
                for (int ns = 0; ns < 4; ++ns)
                    acc[ns][r] = yr[ns * 16 + col];
            }

            // ---- MFMA: [16 edges x 64 cols], K=64 ----
            #pragma unroll
            for (int kc = 0; kc < 2; ++kc) {
                #pragma unroll
                for (int ns = 0; ns < 4; ++ns)
                    acc[ns] = __builtin_amdgcn_mfma_f32_16x16x32_bf16(a[kc], bfr[kc][ns], acc[ns], 0, 0, 0);
            }

            // ---- ReLU -> CT (pad rows write 0) ----
            #pragma unroll
            for (int r = 0; r < 4; ++r) {
                const bool rvalid = (t0 + quad * 4 + r) < ee;
                #pragma unroll
                for (int ns = 0; ns < 4; ++ns)
                    CT[wave][quad * 4 + r][ns * 16 + col] =
                        rvalid ? fmaxf(acc[ns][r], 0.f) : 0.f;
            }
            __builtin_amdgcn_wave_barrier();

            // ---- prefetch next tile's sorted entries (overlaps reduce) ----
            const int t1 = t0 + 16;
            int2 me2;
            if (t1 < ee) me2 = sorted[min(t1 + col, ee - 1)];

            // ---- reduce: batched LDS reads + uniform scalar flush ----
            float cv[16];
            #pragma unroll
            for (int m = 0; m < 16; ++m) cv[m] = CT[wave][m][lane];

            const int mez = me.y;
            #pragma unroll
            for (int m = 0; m < 16; ++m) {
                const int d = (int)((unsigned)__builtin_amdgcn_readlane(mez, m) & 0xffffu);
                if (d != cur) {
                    if (cur >= 0) obase[(size_t)cur * OUT_F] = s;
                    cur = d; s = 0.f;
                }
                s += cv[m];
            }
            cur = __builtin_amdgcn_readfirstlane(cur);
            __builtin_amdgcn_wave_barrier();

            // ---- next tile's A-frags ----
            if (t1 < ee) {
                me = me2;
                const float* __restrict__ ar = edge_attr + (size_t)me.x * EDGE_F;
                #pragma unroll
                for (int kc = 0; kc < 2; ++kc)
                    a[kc] = cvt8(*(const floatx4*)(ar + kc * 32 + quad * 8),
                                 *(const floatx4*)(ar + kc * 32 + quad * 8 + 4));
            }
        }
        if (cur >= 0) obase[(size_t)cur * OUT_F] = s;
    }
}

// ---------------------------------------------------------------------------
// Fallback (ws too small): atomic edge kernel
// ---------------------------------------------------------------------------
__global__ __launch_bounds__(256, 3) void edge_kernel_atomic(
    const float* __restrict__ edge_attr,
    const int*   __restrict__ edge_index,
    const float* __restrict__ W,
    const float* __restrict__ Y,
    float*       __restrict__ out)
{
    const int lane = threadIdx.x & 63;
    const int col  = lane & 15;
    const int quad = lane >> 4;

    short8 bfr[2][8];
    #pragma unroll
    for (int kc = 0; kc < 2; ++kc)
        #pragma unroll
        for (int ns = 0; ns < 8; ++ns) {
            const int n = ns * 16 + col;
            const int krow = kc * 32 + quad * 8;
            short8 v;
            #pragma unroll
            for (int j = 0; j < 8; ++j)
                v[j] = (short)f2bf(W[(krow + j) * OUT_F + n]);
            bfr[kc][ns] = v;
        }

    const int* __restrict__ srcp = edge_index;
    const int* __restrict__ dstp = edge_index + N_EDGES;

    const int gwave  = blockIdx.x * 4 + (threadIdx.x >> 6);
    const int nwaves = gridDim.x * 4;

    for (int t = gwave; t < N_EDGES / 16; t += nwaves) {
        const int e0 = t * 16;
        const float* __restrict__ ar = edge_attr + (size_t)(e0 + col) * EDGE_F;
        short8 a[2];
        #pragma unroll
        for (int kc = 0; kc < 2; ++kc)
            a[kc] = cvt8(*(const floatx4*)(ar + kc * 32 + quad * 8),
                         *(const floatx4*)(ar + kc * 32 + quad * 8 + 4));
        int sr[4], dr[4];
        #pragma unroll
        for (int r = 0; r < 4; ++r) {
            sr[r] = srcp[e0 + quad * 4 + r];
            dr[r] = dstp[e0 + quad * 4 + r];
        }
        floatx4 acc[8];
        #pragma unroll
        for (int ns = 0; ns < 8; ++ns)
            #pragma unroll
            for (int r = 0; r < 4; ++r)
                acc[ns][r] = Y[(size_t)sr[r] * OUT_F + ns * 16 + col];
        #pragma unroll
        for (int kc = 0; kc < 2; ++kc)
            #pragma unroll
            for (int ns = 0; ns < 8; ++ns)
                acc[ns] = __builtin_amdgcn_mfma_f32_16x16x32_bf16(a[kc], bfr[kc][ns], acc[ns], 0, 0, 0);
        #pragma unroll
        for (int ns = 0; ns < 8; ++ns)
            #pragma unroll
            for (int r = 0; r < 4; ++r) {
                const float v = acc[ns][r];
                if (v > 0.0f)
                    atomicAdd(out + (size_t)dr[r] * OUT_F + ns * 16 + col, v);
            }
    }
}

extern "C" void kernel_launch(void* const* d_in, const int* in_sizes, int n_in,
                              void* d_out, int out_size, void* d_ws, size_t ws_size,
                              hipStream_t stream) {
    const float* x          = (const float*)d_in[0];
    const int*   edge_index = (const int*)  d_in[1];
    const float* edge_attr  = (const float*)d_in[2];
    const float* W          = (const float*)d_in[3];
    const float* bias       = (const float*)d_in[4];
    float*       out        = (float*)d_out;

    // workspace layout
    float* Y          = (float*)d_ws;                          // 25.6 MB
    int2*  sorted     = (int2*)(Y + (size_t)N_NODES * OUT_F);  // 6.4 MB
    int*   hist       = (int*)(sorted + N_EDGES);
    int*   chunkSum   = hist + N_NODES;
    int*   chunkBase  = chunkSum + 256;
    int*   row_off    = chunkBase + 256;                       // N_NODES+1
    int*   cursor     = row_off + N_NODES + 1;                 // N_NODES
    int*   range_start= cursor + N_NODES;                      // NRANGES+1
    const size_t needed = (size_t)((char*)(range_start + NRANGES + 1) - (char*)d_ws);

    hipMemsetAsync(out, 0, (size_t)out_size * sizeof(float), stream);
    node_kernel<<<dim3(512), dim3(256), 0, stream>>>(x, W, bias, Y);

    if (ws_size < needed) {
        edge_kernel_atomic<<<dim3(1024), dim3(256), 0, stream>>>(edge_attr, edge_index, W, Y, out);
        return;
    }

    hipMemsetAsync(hist, 0, (size_t)N_NODES * sizeof(int), stream);
    hist_kernel   <<<dim3(2048), dim3(256), 0, stream>>>(edge_index, hist);
    scan1_kernel  <<<dim3(NCH),  dim3(256), 0, stream>>>(hist, chunkSum);
    scan2_kernel  <<<dim3(1),    dim3(256), 0, stream>>>(chunkSum, chunkBase);
    scan3_kernel  <<<dim3(NCH),  dim3(256), 0, stream>>>(hist, chunkBase, row_off, cursor);
    range_kernel  <<<dim3((NRANGES + 256) / 256), dim3(256), 0, stream>>>(row_off, range_start);
    scatter_kernel<<<dim3(2048), dim3(256), 0, stream>>>(edge_index, cursor, sorted);
    edge_gemm     <<<dim3(1536), dim3(256), 0, stream>>>(
        edge_attr, W, Y, range_start, sorted, out);
}